// Round 3
// baseline (315.324 us; speedup 1.0000x reference)
//
#include <hip/hip_runtime.h>
#include <math.h>

#define N_NODES 65536
#define B_GRAPHS 64
#define NPG 1024
#define EPG 16384
#define E_TOTAL (B_GRAPHS * EPG)
#define NEG 0.2f

typedef float f32x4 __attribute__((ext_vector_type(4)));
typedef __bf16 bf16x8 __attribute__((ext_vector_type(8)));
typedef int i32x4 __attribute__((ext_vector_type(4)));
typedef unsigned int uint32;
typedef unsigned short ushort16;

union FragU { i32x4 i; bf16x8 v; uint32 u[4]; };

// split f32 pair -> packed bf16 hi dword + lo dword (elem0 in low 16 bits)
__device__ __forceinline__ void cvt_pair(float a, float b, uint32& hi, uint32& lo) {
    uint32 ia = __float_as_uint(a), ib = __float_as_uint(b);
    uint32 ha = ia & 0xFFFF0000u, hb = ib & 0xFFFF0000u;
    hi = (ia >> 16) | hb;
    float ra = a - __uint_as_float(ha);
    float rb = b - __uint_as_float(hb);
    lo = (__float_as_uint(ra) >> 16) | (__float_as_uint(rb) & 0xFFFF0000u);
}

// ---------------- DPP 16-lane reduce (head groups = DPP rows) ----------------
template <int CTRL>
__device__ __forceinline__ float dpp_add(float v) {
    int x = __builtin_amdgcn_update_dpp(0, __float_as_int(v), CTRL, 0xf, 0xf, true);
    return v + __int_as_float(x);
}
__device__ __forceinline__ float hsum16(float v) {
    v = dpp_add<0xB1>(v);   // quad_perm [1,0,3,2]  (xor 1)
    v = dpp_add<0x4E>(v);   // quad_perm [2,3,0,1]  (xor 2)
    v = dpp_add<0x124>(v);  // row_ror:4
    v = dpp_add<0x128>(v);  // row_ror:8
    return v;
}

// ---------------- CSR build ----------------
__global__ void k_deg(const int* __restrict__ dst, int* __restrict__ cnt) {
    int i = blockIdx.x * 256 + threadIdx.x;
    if (i < E_TOTAL) atomicAdd(&cnt[dst[i]], 1);
}

__global__ __launch_bounds__(256) void k_scan(int* __restrict__ cursor, int* __restrict__ rowptr) {
    int b = blockIdx.x, tid = threadIdx.x;
    __shared__ int ps[256];
    int idx = b * NPG + tid * 4;
    int v0 = cursor[idx], v1 = cursor[idx + 1], v2 = cursor[idx + 2], v3 = cursor[idx + 3];
    ps[tid] = v0 + v1 + v2 + v3;
    __syncthreads();
    for (int off = 1; off < 256; off <<= 1) {
        int u = (tid >= off) ? ps[tid - off] : 0;
        __syncthreads();
        ps[tid] += u;
        __syncthreads();
    }
    int ex = (tid ? ps[tid - 1] : 0) + b * EPG;
    int r0 = ex, r1 = r0 + v0, r2 = r1 + v1, r3 = r2 + v2;
    rowptr[idx] = r0; rowptr[idx + 1] = r1; rowptr[idx + 2] = r2; rowptr[idx + 3] = r3;
    cursor[idx] = r0; cursor[idx + 1] = r1; cursor[idx + 2] = r2; cursor[idx + 3] = r3;
    if (b == 0 && tid == 0) rowptr[N_NODES] = E_TOTAL;
}

__global__ void k_scatter(const int* __restrict__ src, const int* __restrict__ dst,
                          int* __restrict__ cursor, int* __restrict__ col) {
    int i = blockIdx.x * 256 + threadIdx.x;
    if (i < E_TOTAL) {
        int d = dst[i];
        int p = atomicAdd(&cursor[d], 1);
        col[p] = src[i];
    }
}

// ---------------- W transpose + bf16 hi/lo split ----------------
// Wt1 layout: [(mat*2+plane)*128 + n]*128 + k   (ushort), mat0=Ws1, mat1=Wd1
// Wt2 layout: [(mat*2+plane)*128 + n]*32  + k
__global__ __launch_bounds__(256) void k_wconv(const float* __restrict__ Ws1, const float* __restrict__ Wd1,
                                               const float* __restrict__ Ws2, const float* __restrict__ Wd2,
                                               ushort16* __restrict__ Wt1, ushort16* __restrict__ Wt2) {
    int id = blockIdx.x * 256 + threadIdx.x;   // 40960 total
    if (id < 32768) {
        int mat = id >> 14, rem = id & 16383, n = rem >> 7, k = rem & 127;
        float v = (mat ? Wd1 : Ws1)[k * 128 + n];
        uint32 iv = __float_as_uint(v), h = iv & 0xFFFF0000u;
        float r = v - __uint_as_float(h);
        Wt1[((mat * 2 + 0) * 128 + n) * 128 + k] = (ushort16)(iv >> 16);
        Wt1[((mat * 2 + 1) * 128 + n) * 128 + k] = (ushort16)(__float_as_uint(r) >> 16);
    } else if (id < 40960) {
        int id2 = id - 32768;
        int mat = id2 >> 12, rem = id2 & 4095, n = rem >> 5, k = rem & 31;
        float v = (mat ? Wd2 : Ws2)[k * 128 + n];
        uint32 iv = __float_as_uint(v), h = iv & 0xFFFF0000u;
        float r = v - __uint_as_float(h);
        Wt2[((mat * 2 + 0) * 128 + n) * 32 + k] = (ushort16)(iv >> 16);
        Wt2[((mat * 2 + 1) * 128 + n) * 32 + k] = (ushort16)(__float_as_uint(r) >> 16);
    }
}

// ---------------- MFMA dual GEMM: fs = X@Ws+bs, fd = X@Wd+bd via bf16x3 ----------------
// one wave = 16 rows x 256 cols; A kept in registers (hi/lo frags); B from Wt (L1/L2).
template <int K>
__global__ __launch_bounds__(256) void k_gemm_mfma(const float* __restrict__ X,
                                                   const ushort16* __restrict__ Wt,
                                                   const float* __restrict__ bs, const float* __restrict__ bd,
                                                   float* __restrict__ outs, float* __restrict__ outd) {
    constexpr int NC = K / 32;
    int lane = threadIdx.x & 63, wv = threadIdx.x >> 6;
    int row = blockIdx.x * 64 + wv * 16 + (lane & 15);
    int kg = lane >> 4;                     // k-group 0..3

    // load A rows once, split to hi/lo bf16 fragments in registers
    FragU ah[NC], al[NC];
    const float* xr = X + (size_t)row * K + kg * 8;
#pragma unroll
    for (int c = 0; c < NC; ++c) {
        float4 v0 = *(const float4*)(xr + c * 32);
        float4 v1 = *(const float4*)(xr + c * 32 + 4);
        cvt_pair(v0.x, v0.y, ah[c].u[0], al[c].u[0]);
        cvt_pair(v0.z, v0.w, ah[c].u[1], al[c].u[1]);
        cvt_pair(v1.x, v1.y, ah[c].u[2], al[c].u[2]);
        cvt_pair(v1.z, v1.w, ah[c].u[3], al[c].u[3]);
    }

    f32x4 acc[16];
#pragma unroll
    for (int t = 0; t < 16; ++t) acc[t] = (f32x4){0.f, 0.f, 0.f, 0.f};

#pragma unroll
    for (int c = 0; c < NC; ++c) {
#pragma unroll
        for (int nt = 0; nt < 16; ++nt) {
            const ushort16* wb = Wt + ((size_t)((nt >> 3) * 2 * 128 + (nt & 7) * 16 + (lane & 15))) * K
                                 + c * 32 + kg * 8;
            FragU bh, bl;
            bh.i = *(const i32x4*)wb;
            bl.i = *(const i32x4*)(wb + 128 * K);   // lo plane is +128 n-rows
            acc[nt] = __builtin_amdgcn_mfma_f32_16x16x32_bf16(ah[c].v, bh.v, acc[nt], 0, 0, 0);
            acc[nt] = __builtin_amdgcn_mfma_f32_16x16x32_bf16(ah[c].v, bl.v, acc[nt], 0, 0, 0);
            acc[nt] = __builtin_amdgcn_mfma_f32_16x16x32_bf16(al[c].v, bh.v, acc[nt], 0, 0, 0);
        }
    }

    // epilogue: C/D layout col = lane&15, row = (lane>>4)*4 + reg  [verified m89]
    int orow = blockIdx.x * 64 + wv * 16 + (lane >> 4) * 4;
    int ocol = lane & 15;
#pragma unroll
    for (int nt = 0; nt < 16; ++nt) {
        const float* bp = (nt < 8) ? bs : bd;
        float bb = bp[(nt & 7) * 16 + ocol];
        float* ob = (nt < 8) ? outs : outd;
        float* p = ob + (size_t)orow * 128 + (nt & 7) * 16 + ocol;
#pragma unroll
        for (int r = 0; r < 4; ++r)
            p[(size_t)r * 128] = acc[nt][r] + bb;
    }
}

// ---------------- GATv2 edge aggregation + head maxpool ----------------
__global__ __launch_bounds__(256) void k_edge(const float* __restrict__ fs, const float* __restrict__ fd,
                                              const int* __restrict__ rowptr, const int* __restrict__ col,
                                              const float* __restrict__ attn, float* __restrict__ hout) {
    int w = threadIdx.x >> 6, lane = threadIdx.x & 63;
    int n = blockIdx.x * 4 + w;
    float2 av = ((const float2*)attn)[lane];
    av.x *= 1.44269504089f;
    av.y *= 1.44269504089f;
    float2 fdv = *(const float2*)(fd + ((size_t)n << 7) + (lane << 1));
    int start = __builtin_amdgcn_readfirstlane(rowptr[n]);
    int end   = __builtin_amdgcn_readfirstlane(rowptr[n + 1]);
    float z = 0.f, a0 = 0.f, a1 = 0.f;
    float z2 = 0.f, b0 = 0.f, b1 = 0.f;
    for (int j = start; j < end; j += 8) {
        int rem = end - j;
        int sv[8];
        float2 fv[8];
        float p[8];
#pragma unroll
        for (int u = 0; u < 8; ++u) {
            int jj = j + ((u < rem) ? u : rem - 1);
            sv[u] = col[jj];
        }
#pragma unroll
        for (int u = 0; u < 8; ++u)
            fv[u] = *(const float2*)(fs + ((size_t)sv[u] << 7) + (lane << 1));
#pragma unroll
        for (int u = 0; u < 8; ++u) {
            float e0 = fv[u].x + fdv.x; e0 = fmaxf(e0, NEG * e0);
            float e1 = fv[u].y + fdv.y; e1 = fmaxf(e1, NEG * e1);
            float sp = fmaf(e1, av.y, e0 * av.x);
            sp = hsum16(sp);
            sp = fminf(fmaxf(sp, -80.f), 80.f);
            float pe = exp2f(sp);
            p[u] = (u < rem) ? pe : 0.f;
        }
#pragma unroll
        for (int u = 0; u < 8; u += 2) {
            z  += p[u];     a0 = fmaf(p[u],     fv[u].x,     a0); a1 = fmaf(p[u],     fv[u].y,     a1);
            z2 += p[u + 1]; b0 = fmaf(p[u + 1], fv[u + 1].x, b0); b1 = fmaf(p[u + 1], fv[u + 1].y, b1);
        }
    }
    z += z2; a0 += b0; a1 += b1;
    float r = (z > 0.f) ? 1.f / z : 0.f;
    a0 *= r; a1 *= r;
    a0 = fmaxf(a0, __shfl_xor(a0, 16)); a0 = fmaxf(a0, __shfl_xor(a0, 32));
    a1 = fmaxf(a1, __shfl_xor(a1, 16)); a1 = fmaxf(a1, __shfl_xor(a1, 32));
    if (lane < 16)
        *(float2*)(hout + ((size_t)n << 5) + (lane << 1)) = make_float2(a0, a1);
}

// ---------------- global attention pooling ----------------
__global__ __launch_bounds__(256) void k_pool(const float* __restrict__ h2, const float* __restrict__ gW,
                                              const float* __restrict__ gb, float* __restrict__ out) {
    int b = blockIdx.x, tid = threadIdx.x;
    __shared__ float ga[NPG];
    __shared__ float red[256];
    __shared__ float gws[32];
    const float* hb = h2 + (size_t)b * NPG * 32;
    if (tid < 32) gws[tid] = gW[tid];
    __syncthreads();
    float gbv = gb[0];
    float lmax = -INFINITY;
    float gloc[4];
#pragma unroll
    for (int j = 0; j < 4; ++j) {
        int nl = tid + j * 256;
        const float* row = hb + nl * 32;
        float dot = 0.f;
#pragma unroll
        for (int c = 0; c < 32; c += 4) {
            float4 v = *(const float4*)(row + c);
            dot += v.x * gws[c] + v.y * gws[c + 1] + v.z * gws[c + 2] + v.w * gws[c + 3];
        }
        gloc[j] = dot + gbv;
        lmax = fmaxf(lmax, gloc[j]);
    }
    red[tid] = lmax; __syncthreads();
    for (int s2 = 128; s2 > 0; s2 >>= 1) { if (tid < s2) red[tid] = fmaxf(red[tid], red[tid + s2]); __syncthreads(); }
    float m = red[0];
    __syncthreads();
    float lsum = 0.f;
#pragma unroll
    for (int j = 0; j < 4; ++j) {
        int nl = tid + j * 256;
        float a = __expf(gloc[j] - m);
        ga[nl] = a;
        lsum += a;
    }
    red[tid] = lsum; __syncthreads();
    for (int s2 = 128; s2 > 0; s2 >>= 1) { if (tid < s2) red[tid] += red[tid + s2]; __syncthreads(); }
    float z = red[0];
    __syncthreads();
    int d = tid & 31, ng = tid >> 5;
    float acc = 0.f;
    for (int nl = ng; nl < NPG; nl += 8) acc += ga[nl] * hb[nl * 32 + d];
    red[tid] = acc; __syncthreads();
    if (tid < 32) {
        float s = red[tid];
#pragma unroll
        for (int g2 = 1; g2 < 8; ++g2) s += red[g2 * 32 + tid];
        out[b * 32 + tid] = s / z;
    }
}

extern "C" void kernel_launch(void* const* d_in, const int* in_sizes, int n_in,
                              void* d_out, int out_size, void* d_ws, size_t ws_size,
                              hipStream_t stream) {
    const float* x     = (const float*)d_in[0];
    const int*   src   = (const int*)d_in[1];
    const int*   dst   = (const int*)d_in[2];
    const float* Ws1   = (const float*)d_in[4];
    const float* bs1   = (const float*)d_in[5];
    const float* Wd1   = (const float*)d_in[6];
    const float* bd1   = (const float*)d_in[7];
    const float* attn1 = (const float*)d_in[8];
    const float* Ws2   = (const float*)d_in[9];
    const float* bs2   = (const float*)d_in[10];
    const float* Wd2   = (const float*)d_in[11];
    const float* bd2   = (const float*)d_in[12];
    const float* attn2 = (const float*)d_in[13];
    const float* gW    = (const float*)d_in[14];
    const float* gb    = (const float*)d_in[15];
    float* out = (float*)d_out;

    // workspace layout (~89 MB, same footprint as before)
    float* fs = (float*)d_ws;                        // N*128
    float* fd = fs + (size_t)N_NODES * 128;          // N*128
    float* h1 = fd + (size_t)N_NODES * 128;          // N*32
    float* h2 = h1 + (size_t)N_NODES * 32;           // N*32
    int* rowptr = (int*)(h2 + (size_t)N_NODES * 32); // N+1
    int* cursor = rowptr + (N_NODES + 4);            // N
    int* col    = cursor + N_NODES;                  // E
    // Wt planes live INSIDE the h2 region (160KB << 8.4MB); consumed by gemm1/gemm2,
    // clobbered only later by k_edge layer-2 writing h2 (strictly after gemm2 in stream order).
    ushort16* Wt1 = (ushort16*)h2;                   // 4*128*128 ushort = 128KB
    ushort16* Wt2 = Wt1 + 4 * 128 * 128;             // 4*128*32  ushort =  32KB

    // W conversion + CSR build
    k_wconv<<<160, 256, 0, stream>>>(Ws1, Wd1, Ws2, Wd2, Wt1, Wt2);
    hipMemsetAsync(cursor, 0, N_NODES * sizeof(int), stream);
    k_deg<<<E_TOTAL / 256, 256, 0, stream>>>(dst, cursor);
    k_scan<<<B_GRAPHS, 256, 0, stream>>>(cursor, rowptr);
    k_scatter<<<E_TOTAL / 256, 256, 0, stream>>>(src, dst, cursor, col);

    // layer 1
    k_gemm_mfma<128><<<N_NODES / 64, 256, 0, stream>>>(x, Wt1, bs1, bd1, fs, fd);
    k_edge<<<N_NODES / 4, 256, 0, stream>>>(fs, fd, rowptr, col, attn1, h1);

    // layer 2
    k_gemm_mfma<32><<<N_NODES / 64, 256, 0, stream>>>(h1, Wt2, bs2, bd2, fs, fd);
    k_edge<<<N_NODES / 4, 256, 0, stream>>>(fs, fd, rowptr, col, attn2, h2);

    // global attention pooling
    k_pool<<<B_GRAPHS, 256, 0, stream>>>(h2, gW, gb, out);
}

// Round 4
// 274.791 us; speedup vs baseline: 1.1475x; 1.1475x over previous
//
#include <hip/hip_runtime.h>
#include <math.h>

#define N_NODES 65536
#define B_GRAPHS 64
#define NPG 1024
#define EPG 16384
#define E_TOTAL (B_GRAPHS * EPG)
#define NEG 0.2f

typedef float f32x4 __attribute__((ext_vector_type(4)));
typedef __bf16 bf16x8 __attribute__((ext_vector_type(8)));
typedef int i32x4 __attribute__((ext_vector_type(4)));
typedef unsigned int uint32;
typedef unsigned short u16;

union FragU { i32x4 i; bf16x8 v; uint32 u[4]; };

// split f32 pair -> packed bf16 hi dword + lo dword (elem0 in low 16 bits)
__device__ __forceinline__ void cvt_pair(float a, float b, uint32& hi, uint32& lo) {
    uint32 ia = __float_as_uint(a), ib = __float_as_uint(b);
    uint32 ha = ia & 0xFFFF0000u, hb = ib & 0xFFFF0000u;
    hi = (ia >> 16) | hb;
    float ra = a - __uint_as_float(ha);
    float rb = b - __uint_as_float(hb);
    lo = (__float_as_uint(ra) >> 16) | (__float_as_uint(rb) & 0xFFFF0000u);
}

// ---------------- DPP 16-lane reduce (head groups = DPP rows) ----------------
template <int CTRL>
__device__ __forceinline__ float dpp_add(float v) {
    int x = __builtin_amdgcn_update_dpp(0, __float_as_int(v), CTRL, 0xf, 0xf, true);
    return v + __int_as_float(x);
}
__device__ __forceinline__ float hsum16(float v) {
    v = dpp_add<0xB1>(v);   // quad_perm [1,0,3,2]  (xor 1)
    v = dpp_add<0x4E>(v);   // quad_perm [2,3,0,1]  (xor 2)
    v = dpp_add<0x124>(v);  // row_ror:4
    v = dpp_add<0x128>(v);  // row_ror:8
    return v;
}

// ---------------- CSR build ----------------
__global__ void k_deg(const int* __restrict__ dst, int* __restrict__ cnt) {
    int i = blockIdx.x * 256 + threadIdx.x;
    if (i < E_TOTAL) atomicAdd(&cnt[dst[i]], 1);
}

__global__ __launch_bounds__(256) void k_scan(int* __restrict__ cursor, int* __restrict__ rowptr) {
    int b = blockIdx.x, tid = threadIdx.x;
    __shared__ int ps[256];
    int idx = b * NPG + tid * 4;
    int v0 = cursor[idx], v1 = cursor[idx + 1], v2 = cursor[idx + 2], v3 = cursor[idx + 3];
    ps[tid] = v0 + v1 + v2 + v3;
    __syncthreads();
    for (int off = 1; off < 256; off <<= 1) {
        int u = (tid >= off) ? ps[tid - off] : 0;
        __syncthreads();
        ps[tid] += u;
        __syncthreads();
    }
    int ex = (tid ? ps[tid - 1] : 0) + b * EPG;
    int r0 = ex, r1 = r0 + v0, r2 = r1 + v1, r3 = r2 + v2;
    rowptr[idx] = r0; rowptr[idx + 1] = r1; rowptr[idx + 2] = r2; rowptr[idx + 3] = r3;
    cursor[idx] = r0; cursor[idx + 1] = r1; cursor[idx + 2] = r2; cursor[idx + 3] = r3;
    if (b == 0 && tid == 0) rowptr[N_NODES] = E_TOTAL;
}

__global__ void k_scatter(const int* __restrict__ src, const int* __restrict__ dst,
                          int* __restrict__ cursor, int* __restrict__ col) {
    int i = blockIdx.x * 256 + threadIdx.x;
    if (i < E_TOTAL) {
        int d = dst[i];
        int p = atomicAdd(&cursor[d], 1);
        col[p] = src[i];
    }
}

// ---------------- W transpose + bf16 hi/lo split ----------------
// Wt1 layout: [(mat*2+plane)*128 + n]*128 + k   (u16), mat0=Ws1, mat1=Wd1
// Wt2 layout: [(mat*2+plane)*128 + n]*32  + k
__global__ __launch_bounds__(256) void k_wconv(const float* __restrict__ Ws1, const float* __restrict__ Wd1,
                                               const float* __restrict__ Ws2, const float* __restrict__ Wd2,
                                               u16* __restrict__ Wt1, u16* __restrict__ Wt2) {
    int id = blockIdx.x * 256 + threadIdx.x;   // 40960 total
    if (id < 32768) {
        int mat = id >> 14, rem = id & 16383, n = rem >> 7, k = rem & 127;
        float v = (mat ? Wd1 : Ws1)[k * 128 + n];
        uint32 iv = __float_as_uint(v), h = iv & 0xFFFF0000u;
        float r = v - __uint_as_float(h);
        Wt1[((mat * 2 + 0) * 128 + n) * 128 + k] = (u16)(iv >> 16);
        Wt1[((mat * 2 + 1) * 128 + n) * 128 + k] = (u16)(__float_as_uint(r) >> 16);
    } else if (id < 40960) {
        int id2 = id - 32768;
        int mat = id2 >> 12, rem = id2 & 4095, n = rem >> 5, k = rem & 31;
        float v = (mat ? Wd2 : Ws2)[k * 128 + n];
        uint32 iv = __float_as_uint(v), h = iv & 0xFFFF0000u;
        float r = v - __uint_as_float(h);
        Wt2[((mat * 2 + 0) * 128 + n) * 32 + k] = (u16)(iv >> 16);
        Wt2[((mat * 2 + 1) * 128 + n) * 32 + k] = (u16)(__float_as_uint(r) >> 16);
    }
}

// ---------------- MFMA dual GEMM: fs = X@Ws+bs, fd = X@Wd+bd via bf16x3 ----------------
// block = 64 rows x 256 cols; B chunks staged in LDS (shared by all waves);
// wave wv owns col-tiles wv*4..wv*4+3 across ALL 64 rows (4 A row-sets in regs).
template <int K>
__global__ __launch_bounds__(256) void k_gemm_mfma(const float* __restrict__ X,
                                                   const u16* __restrict__ Wt,
                                                   const float* __restrict__ bs, const float* __restrict__ bd,
                                                   float* __restrict__ outs, float* __restrict__ outd) {
    constexpr int NC = K / 32;
    __shared__ u16 bsh[512 * 40];   // 512 rows x 80B (64B data + 16B pad) = 40KB
    int tid = threadIdx.x;
    int lane = tid & 63, wv = tid >> 6;
    int kg = lane >> 4, l15 = lane & 15;
    int nb = blockIdx.x * 64;

    f32x4 acc[4][4];
#pragma unroll
    for (int i = 0; i < 4; ++i)
#pragma unroll
        for (int s = 0; s < 4; ++s) acc[i][s] = (f32x4){0.f, 0.f, 0.f, 0.f};

    for (int c = 0; c < NC; ++c) {
        __syncthreads();   // prev chunk's reads done before overwrite (no-op at c=0)
        // stage B chunk: 512 rows x 64B
#pragma unroll
        for (int j = 0; j < 8; ++j) {
            int idx = tid + j * 256;           // 0..2047
            int R = idx >> 2, seg = idx & 3;
            i32x4 v = *(const i32x4*)(Wt + (size_t)R * K + c * 32 + seg * 8);
            *(i32x4*)(bsh + R * 40 + seg * 8) = v;
        }
        // load + split A chunk: 4 row-sets of 16 rows, 32 k each
        FragU ah[4], al[4];
#pragma unroll
        for (int s = 0; s < 4; ++s) {
            const float* xr = X + (size_t)(nb + s * 16 + l15) * K + c * 32 + kg * 8;
            float4 v0 = *(const float4*)xr;
            float4 v1 = *(const float4*)(xr + 4);
            cvt_pair(v0.x, v0.y, ah[s].u[0], al[s].u[0]);
            cvt_pair(v0.z, v0.w, ah[s].u[1], al[s].u[1]);
            cvt_pair(v1.x, v1.y, ah[s].u[2], al[s].u[2]);
            cvt_pair(v1.z, v1.w, ah[s].u[3], al[s].u[3]);
        }
        __syncthreads();
#pragma unroll
        for (int i = 0; i < 4; ++i) {
            int T = wv * 4 + i;                              // col-tile 0..15
            int Rh = ((T >> 3) * 2) * 128 + (T & 7) * 16 + l15;
            FragU bh, bl;
            bh.i = *(const i32x4*)(bsh + Rh * 40 + kg * 8);
            bl.i = *(const i32x4*)(bsh + (Rh + 128) * 40 + kg * 8);
#pragma unroll
            for (int s = 0; s < 4; ++s) {
                acc[i][s] = __builtin_amdgcn_mfma_f32_16x16x32_bf16(ah[s].v, bh.v, acc[i][s], 0, 0, 0);
                acc[i][s] = __builtin_amdgcn_mfma_f32_16x16x32_bf16(ah[s].v, bl.v, acc[i][s], 0, 0, 0);
                acc[i][s] = __builtin_amdgcn_mfma_f32_16x16x32_bf16(al[s].v, bh.v, acc[i][s], 0, 0, 0);
            }
        }
    }

    // epilogue: C/D layout col = lane&15, row = (lane>>4)*4 + reg  [m89]
#pragma unroll
    for (int i = 0; i < 4; ++i) {
        int T = wv * 4 + i;
        const float* bp = (T < 8) ? bs : bd;
        float* ob = (T < 8) ? outs : outd;
        float bb = bp[(T & 7) * 16 + l15];
#pragma unroll
        for (int s = 0; s < 4; ++s) {
            float* p = ob + (size_t)(nb + s * 16 + kg * 4) * 128 + (T & 7) * 16 + l15;
#pragma unroll
            for (int r = 0; r < 4; ++r)
                p[(size_t)r * 128] = acc[i][s][r] + bb;
        }
    }
}

// ---------------- GATv2 edge aggregation + head maxpool ----------------
__global__ __launch_bounds__(256) void k_edge(const float* __restrict__ fs, const float* __restrict__ fd,
                                              const int* __restrict__ rowptr, const int* __restrict__ col,
                                              const float* __restrict__ attn, float* __restrict__ hout) {
    int w = threadIdx.x >> 6, lane = threadIdx.x & 63;
    int n = blockIdx.x * 4 + w;
    float2 av = ((const float2*)attn)[lane];
    av.x *= 1.44269504089f;
    av.y *= 1.44269504089f;
    float2 fdv = *(const float2*)(fd + ((size_t)n << 7) + (lane << 1));
    int start = __builtin_amdgcn_readfirstlane(rowptr[n]);
    int end   = __builtin_amdgcn_readfirstlane(rowptr[n + 1]);
    float z = 0.f, a0 = 0.f, a1 = 0.f;
    float z2 = 0.f, b0 = 0.f, b1 = 0.f;
    for (int j = start; j < end; j += 8) {
        int rem = end - j;
        int sv[8];
        float2 fv[8];
        float p[8];
#pragma unroll
        for (int u = 0; u < 8; ++u) {
            int jj = j + ((u < rem) ? u : rem - 1);
            sv[u] = col[jj];
        }
#pragma unroll
        for (int u = 0; u < 8; ++u)
            fv[u] = *(const float2*)(fs + ((size_t)sv[u] << 7) + (lane << 1));
#pragma unroll
        for (int u = 0; u < 8; ++u) {
            float e0 = fv[u].x + fdv.x; e0 = fmaxf(e0, NEG * e0);
            float e1 = fv[u].y + fdv.y; e1 = fmaxf(e1, NEG * e1);
            float sp = fmaf(e1, av.y, e0 * av.x);
            sp = hsum16(sp);
            sp = fminf(fmaxf(sp, -80.f), 80.f);
            float pe = exp2f(sp);
            p[u] = (u < rem) ? pe : 0.f;
        }
#pragma unroll
        for (int u = 0; u < 8; u += 2) {
            z  += p[u];     a0 = fmaf(p[u],     fv[u].x,     a0); a1 = fmaf(p[u],     fv[u].y,     a1);
            z2 += p[u + 1]; b0 = fmaf(p[u + 1], fv[u + 1].x, b0); b1 = fmaf(p[u + 1], fv[u + 1].y, b1);
        }
    }
    z += z2; a0 += b0; a1 += b1;
    float r = (z > 0.f) ? 1.f / z : 0.f;
    a0 *= r; a1 *= r;
    a0 = fmaxf(a0, __shfl_xor(a0, 16)); a0 = fmaxf(a0, __shfl_xor(a0, 32));
    a1 = fmaxf(a1, __shfl_xor(a1, 16)); a1 = fmaxf(a1, __shfl_xor(a1, 32));
    if (lane < 16)
        *(float2*)(hout + ((size_t)n << 5) + (lane << 1)) = make_float2(a0, a1);
}

// ---------------- global attention pooling ----------------
__global__ __launch_bounds__(256) void k_pool(const float* __restrict__ h2, const float* __restrict__ gW,
                                              const float* __restrict__ gb, float* __restrict__ out) {
    int b = blockIdx.x, tid = threadIdx.x;
    __shared__ float ga[NPG];
    __shared__ float red[256];
    __shared__ float gws[32];
    const float* hb = h2 + (size_t)b * NPG * 32;
    if (tid < 32) gws[tid] = gW[tid];
    __syncthreads();
    float gbv = gb[0];
    float lmax = -INFINITY;
    float gloc[4];
#pragma unroll
    for (int j = 0; j < 4; ++j) {
        int nl = tid + j * 256;
        const float* row = hb + nl * 32;
        float dot = 0.f;
#pragma unroll
        for (int c = 0; c < 32; c += 4) {
            float4 v = *(const float4*)(row + c);
            dot += v.x * gws[c] + v.y * gws[c + 1] + v.z * gws[c + 2] + v.w * gws[c + 3];
        }
        gloc[j] = dot + gbv;
        lmax = fmaxf(lmax, gloc[j]);
    }
    red[tid] = lmax; __syncthreads();
    for (int s2 = 128; s2 > 0; s2 >>= 1) { if (tid < s2) red[tid] = fmaxf(red[tid], red[tid + s2]); __syncthreads(); }
    float m = red[0];
    __syncthreads();
    float lsum = 0.f;
#pragma unroll
    for (int j = 0; j < 4; ++j) {
        int nl = tid + j * 256;
        float a = __expf(gloc[j] - m);
        ga[nl] = a;
        lsum += a;
    }
    red[tid] = lsum; __syncthreads();
    for (int s2 = 128; s2 > 0; s2 >>= 1) { if (tid < s2) red[tid] += red[tid + s2]; __syncthreads(); }
    float z = red[0];
    __syncthreads();
    int d = tid & 31, ng = tid >> 5;
    float acc = 0.f;
    for (int nl = ng; nl < NPG; nl += 8) acc += ga[nl] * hb[nl * 32 + d];
    red[tid] = acc; __syncthreads();
    if (tid < 32) {
        float s = red[tid];
#pragma unroll
        for (int g2 = 1; g2 < 8; ++g2) s += red[g2 * 32 + tid];
        out[b * 32 + tid] = s / z;
    }
}

extern "C" void kernel_launch(void* const* d_in, const int* in_sizes, int n_in,
                              void* d_out, int out_size, void* d_ws, size_t ws_size,
                              hipStream_t stream) {
    const float* x     = (const float*)d_in[0];
    const int*   src   = (const int*)d_in[1];
    const int*   dst   = (const int*)d_in[2];
    const float* Ws1   = (const float*)d_in[4];
    const float* bs1   = (const float*)d_in[5];
    const float* Wd1   = (const float*)d_in[6];
    const float* bd1   = (const float*)d_in[7];
    const float* attn1 = (const float*)d_in[8];
    const float* Ws2   = (const float*)d_in[9];
    const float* bs2   = (const float*)d_in[10];
    const float* Wd2   = (const float*)d_in[11];
    const float* bd2   = (const float*)d_in[12];
    const float* attn2 = (const float*)d_in[13];
    const float* gW    = (const float*)d_in[14];
    const float* gb    = (const float*)d_in[15];
    float* out = (float*)d_out;

    // workspace layout (~89 MB)
    float* fs = (float*)d_ws;                        // N*128
    float* fd = fs + (size_t)N_NODES * 128;          // N*128
    float* h1 = fd + (size_t)N_NODES * 128;          // N*32
    float* h2 = h1 + (size_t)N_NODES * 32;           // N*32
    int* rowptr = (int*)(h2 + (size_t)N_NODES * 32); // N+1
    int* cursor = rowptr + (N_NODES + 4);            // N
    int* col    = cursor + N_NODES;                  // E
    // Wt planes live INSIDE the h2 region (160KB << 8.4MB); consumed by gemm1/gemm2,
    // clobbered only later by k_edge layer-2 writing h2 (strictly after gemm2).
    u16* Wt1 = (u16*)h2;                             // 4*128*128 u16 = 128KB
    u16* Wt2 = Wt1 + 4 * 128 * 128;                  // 4*128*32  u16 =  32KB

    // W conversion + CSR build
    k_wconv<<<160, 256, 0, stream>>>(Ws1, Wd1, Ws2, Wd2, Wt1, Wt2);
    hipMemsetAsync(cursor, 0, N_NODES * sizeof(int), stream);
    k_deg<<<E_TOTAL / 256, 256, 0, stream>>>(dst, cursor);
    k_scan<<<B_GRAPHS, 256, 0, stream>>>(cursor, rowptr);
    k_scatter<<<E_TOTAL / 256, 256, 0, stream>>>(src, dst, cursor, col);

    // layer 1
    k_gemm_mfma<128><<<N_NODES / 64, 256, 0, stream>>>(x, Wt1, bs1, bd1, fs, fd);
    k_edge<<<N_NODES / 4, 256, 0, stream>>>(fs, fd, rowptr, col, attn1, h1);

    // layer 2
    k_gemm_mfma<32><<<N_NODES / 64, 256, 0, stream>>>(h1, Wt2, bs2, bd2, fs, fd);
    k_edge<<<N_NODES / 4, 256, 0, stream>>>(fs, fd, rowptr, col, attn2, h2);

    // global attention pooling
    k_pool<<<B_GRAPHS, 256, 0, stream>>>(h2, gW, gb, out);
}

// Round 5
// 209.834 us; speedup vs baseline: 1.5027x; 1.3096x over previous
//
#include <hip/hip_runtime.h>
#include <math.h>

#define N_NODES 65536
#define B_GRAPHS 64
#define NPG 1024
#define EPG 16384
#define E_TOTAL (B_GRAPHS * EPG)
#define NEG 0.2f

typedef float f32x4 __attribute__((ext_vector_type(4)));
typedef __bf16 bf16x8 __attribute__((ext_vector_type(8)));
typedef int i32x4 __attribute__((ext_vector_type(4)));
typedef unsigned int uint32;
typedef unsigned short u16;

union FragU { i32x4 i; bf16x8 v; uint32 u[4]; };

// split f32 pair -> packed bf16 hi dword + lo dword (elem0 in low 16 bits)
__device__ __forceinline__ void cvt_pair(float a, float b, uint32& hi, uint32& lo) {
    uint32 ia = __float_as_uint(a), ib = __float_as_uint(b);
    uint32 ha = ia & 0xFFFF0000u, hb = ib & 0xFFFF0000u;
    hi = (ia >> 16) | hb;
    float ra = a - __uint_as_float(ha);
    float rb = b - __uint_as_float(hb);
    lo = (__float_as_uint(ra) >> 16) | (__float_as_uint(rb) & 0xFFFF0000u);
}

// raw v_exp_f32 (2^x) — logits bounded by construction, no range handling needed
__device__ __forceinline__ float fast_exp2(float x) {
    float r;
    asm("v_exp_f32 %0, %1" : "=v"(r) : "v"(x));
    return r;
}

// ---------------- DPP 16-lane reduce (head groups = DPP rows) ----------------
template <int CTRL>
__device__ __forceinline__ float dpp_add(float v) {
    int x = __builtin_amdgcn_update_dpp(0, __float_as_int(v), CTRL, 0xf, 0xf, true);
    return v + __int_as_float(x);
}
__device__ __forceinline__ float hsum16(float v) {
    v = dpp_add<0xB1>(v);   // quad_perm [1,0,3,2]  (xor 1)
    v = dpp_add<0x4E>(v);   // quad_perm [2,3,0,1]  (xor 2)
    v = dpp_add<0x124>(v);  // row_ror:4
    v = dpp_add<0x128>(v);  // row_ror:8
    return v;
}

// ---------------- CSR build: one block per graph, LDS count-sort ----------------
__global__ __launch_bounds__(1024) void k_csr(const int* __restrict__ src, const int* __restrict__ dst,
                                              int* __restrict__ rowptr, int* __restrict__ col) {
    __shared__ int cnt[NPG];
    __shared__ int tmp[NPG];
    __shared__ int scol[EPG];   // 64KB
    int g = blockIdx.x, tid = threadIdx.x;
    int ebase = g * EPG;
    cnt[tid] = 0;
    __syncthreads();
    // pass 1: histogram of local dst
    for (int e = tid; e < EPG; e += 1024)
        atomicAdd(&cnt[dst[ebase + e] & (NPG - 1)], 1);
    __syncthreads();
    // inclusive Hillis-Steele scan, 10 steps, ping-pong cnt<->tmp (ends in cnt)
    int* a = cnt; int* b = tmp;
#pragma unroll
    for (int off = 1; off < 1024; off <<= 1) {
        int u = a[tid] + ((tid >= off) ? a[tid - off] : 0);
        __syncthreads();
        b[tid] = u;
        __syncthreads();
        int* t = a; a = b; b = t;
    }
    int excl = tid ? a[tid - 1] : 0;
    rowptr[g * NPG + tid] = ebase + excl;
    if (g == B_GRAPHS - 1 && tid == 0) rowptr[N_NODES] = E_TOTAL;
    b[tid] = excl;   // scatter cursors (b == the non-result buffer)
    __syncthreads();
    // pass 2: scatter into LDS (sorted by dst)
    for (int e = tid; e < EPG; e += 1024) {
        int d = dst[ebase + e] & (NPG - 1);
        int p = atomicAdd(&b[d], 1);
        scol[p] = src[ebase + e];
    }
    __syncthreads();
    // coalesced writeback
    int4* cg = (int4*)(col + ebase);
    const int4* cs = (const int4*)scol;
    for (int i = tid; i < EPG / 4; i += 1024) cg[i] = cs[i];
}

// ---------------- W transpose + bf16 hi/lo split ----------------
__global__ __launch_bounds__(256) void k_wconv(const float* __restrict__ Ws1, const float* __restrict__ Wd1,
                                               const float* __restrict__ Ws2, const float* __restrict__ Wd2,
                                               u16* __restrict__ Wt1, u16* __restrict__ Wt2) {
    int id = blockIdx.x * 256 + threadIdx.x;   // 40960 total
    if (id < 32768) {
        int mat = id >> 14, rem = id & 16383, n = rem >> 7, k = rem & 127;
        float v = (mat ? Wd1 : Ws1)[k * 128 + n];
        uint32 iv = __float_as_uint(v), h = iv & 0xFFFF0000u;
        float r = v - __uint_as_float(h);
        Wt1[((mat * 2 + 0) * 128 + n) * 128 + k] = (u16)(iv >> 16);
        Wt1[((mat * 2 + 1) * 128 + n) * 128 + k] = (u16)(__float_as_uint(r) >> 16);
    } else if (id < 40960) {
        int id2 = id - 32768;
        int mat = id2 >> 12, rem = id2 & 4095, n = rem >> 5, k = rem & 31;
        float v = (mat ? Wd2 : Ws2)[k * 128 + n];
        uint32 iv = __float_as_uint(v), h = iv & 0xFFFF0000u;
        float r = v - __uint_as_float(h);
        Wt2[((mat * 2 + 0) * 128 + n) * 32 + k] = (u16)(iv >> 16);
        Wt2[((mat * 2 + 1) * 128 + n) * 32 + k] = (u16)(__float_as_uint(r) >> 16);
    }
}

// ---------------- MFMA dual GEMM (unchanged from R4) ----------------
template <int K>
__global__ __launch_bounds__(256) void k_gemm_mfma(const float* __restrict__ X,
                                                   const u16* __restrict__ Wt,
                                                   const float* __restrict__ bs, const float* __restrict__ bd,
                                                   float* __restrict__ outs, float* __restrict__ outd) {
    constexpr int NC = K / 32;
    __shared__ u16 bsh[512 * 40];   // 512 rows x 80B (64B data + 16B pad)
    int tid = threadIdx.x;
    int lane = tid & 63, wv = tid >> 6;
    int kg = lane >> 4, l15 = lane & 15;
    int nb = blockIdx.x * 64;

    f32x4 acc[4][4];
#pragma unroll
    for (int i = 0; i < 4; ++i)
#pragma unroll
        for (int s = 0; s < 4; ++s) acc[i][s] = (f32x4){0.f, 0.f, 0.f, 0.f};

    for (int c = 0; c < NC; ++c) {
        __syncthreads();
#pragma unroll
        for (int j = 0; j < 8; ++j) {
            int idx = tid + j * 256;
            int R = idx >> 2, seg = idx & 3;
            i32x4 v = *(const i32x4*)(Wt + (size_t)R * K + c * 32 + seg * 8);
            *(i32x4*)(bsh + R * 40 + seg * 8) = v;
        }
        FragU ah[4], al[4];
#pragma unroll
        for (int s = 0; s < 4; ++s) {
            const float* xr = X + (size_t)(nb + s * 16 + l15) * K + c * 32 + kg * 8;
            float4 v0 = *(const float4*)xr;
            float4 v1 = *(const float4*)(xr + 4);
            cvt_pair(v0.x, v0.y, ah[s].u[0], al[s].u[0]);
            cvt_pair(v0.z, v0.w, ah[s].u[1], al[s].u[1]);
            cvt_pair(v1.x, v1.y, ah[s].u[2], al[s].u[2]);
            cvt_pair(v1.z, v1.w, ah[s].u[3], al[s].u[3]);
        }
        __syncthreads();
#pragma unroll
        for (int i = 0; i < 4; ++i) {
            int T = wv * 4 + i;
            int Rh = ((T >> 3) * 2) * 128 + (T & 7) * 16 + l15;
            FragU bh, bl;
            bh.i = *(const i32x4*)(bsh + Rh * 40 + kg * 8);
            bl.i = *(const i32x4*)(bsh + (Rh + 128) * 40 + kg * 8);
#pragma unroll
            for (int s = 0; s < 4; ++s) {
                acc[i][s] = __builtin_amdgcn_mfma_f32_16x16x32_bf16(ah[s].v, bh.v, acc[i][s], 0, 0, 0);
                acc[i][s] = __builtin_amdgcn_mfma_f32_16x16x32_bf16(ah[s].v, bl.v, acc[i][s], 0, 0, 0);
                acc[i][s] = __builtin_amdgcn_mfma_f32_16x16x32_bf16(al[s].v, bh.v, acc[i][s], 0, 0, 0);
            }
        }
    }
#pragma unroll
    for (int i = 0; i < 4; ++i) {
        int T = wv * 4 + i;
        const float* bp = (T < 8) ? bs : bd;
        float* ob = (T < 8) ? outs : outd;
        float bb = bp[(T & 7) * 16 + l15];
#pragma unroll
        for (int s = 0; s < 4; ++s) {
            float* p = ob + (size_t)(nb + s * 16 + kg * 4) * 128 + (T & 7) * 16 + l15;
#pragma unroll
            for (int r = 0; r < 4; ++r)
                p[(size_t)r * 128] = acc[i][s][r] + bb;
        }
    }
}

// ---------------- GATv2 edge aggregation + head maxpool ----------------
// one wave per dst node; lane l owns dims (2l,2l+1); head = lane>>4 = DPP row.
// col indices broadcast via readlane -> SGPR base -> saddr loads (no per-edge VALU addr math).
__global__ __launch_bounds__(256) void k_edge(const float* __restrict__ fs, const float* __restrict__ fd,
                                              const int* __restrict__ rowptr, const int* __restrict__ col,
                                              const float* __restrict__ attn, float* __restrict__ hout) {
    int w = threadIdx.x >> 6, lane = threadIdx.x & 63;
    // XCD-aware swizzle: 16384 blocks = 8 XCDs x 2048 -> each XCD owns 8 contiguous graphs
    int bid = blockIdx.x;
    int nb = (bid & 7) * 2048 + (bid >> 3);
    int n = nb * 4 + w;
    float2 av = ((const float2*)attn)[lane];
    av.x *= 1.44269504089f;
    av.y *= 1.44269504089f;
    float2 fdv = *(const float2*)(fd + ((size_t)n << 7) + (lane << 1));
    int start = __builtin_amdgcn_readfirstlane(rowptr[n]);
    int end   = __builtin_amdgcn_readfirstlane(rowptr[n + 1]);
    int l7 = lane & 7;
    float z = 0.f, a0 = 0.f, a1 = 0.f;
    float z2 = 0.f, b0 = 0.f, b1 = 0.f;

    int nfull = (end - start) >> 3;
    int j = start;
    for (int c = 0; c < nfull; ++c, j += 8) {
        int myc = col[j + l7];                   // 8 srcs in lanes 0-7 (replicated per 8)
        float2 fv[8];
#pragma unroll
        for (int u = 0; u < 8; ++u) {
            int sg = __builtin_amdgcn_readlane(myc, u);   // SGPR
            fv[u] = *(const float2*)(fs + ((size_t)(uint32)sg << 7) + (lane << 1));
        }
#pragma unroll
        for (int u = 0; u < 8; ++u) {
            float e0 = fv[u].x + fdv.x; e0 = fmaxf(e0, NEG * e0);
            float e1 = fv[u].y + fdv.y; e1 = fmaxf(e1, NEG * e1);
            float sp = fmaf(e1, av.y, e0 * av.x);
            sp = hsum16(sp);
            float pe = fast_exp2(sp);
            if (u & 1) { z2 += pe; b0 = fmaf(pe, fv[u].x, b0); b1 = fmaf(pe, fv[u].y, b1); }
            else       { z  += pe; a0 = fmaf(pe, fv[u].x, a0); a1 = fmaf(pe, fv[u].y, a1); }
        }
    }
    int rem = end - j;
    if (rem > 0) {
        int jj = j + l7; jj = (jj < end) ? jj : end - 1;
        int myc = col[jj];
        float2 fv[8];
#pragma unroll
        for (int u = 0; u < 8; ++u) {
            int sg = __builtin_amdgcn_readlane(myc, u);
            fv[u] = *(const float2*)(fs + ((size_t)(uint32)sg << 7) + (lane << 1));
        }
#pragma unroll
        for (int u = 0; u < 8; ++u) {
            float e0 = fv[u].x + fdv.x; e0 = fmaxf(e0, NEG * e0);
            float e1 = fv[u].y + fdv.y; e1 = fmaxf(e1, NEG * e1);
            float sp = fmaf(e1, av.y, e0 * av.x);
            sp = hsum16(sp);
            float pe = fast_exp2(sp);
            pe = (u < rem) ? pe : 0.f;
            if (u & 1) { z2 += pe; b0 = fmaf(pe, fv[u].x, b0); b1 = fmaf(pe, fv[u].y, b1); }
            else       { z  += pe; a0 = fmaf(pe, fv[u].x, a0); a1 = fmaf(pe, fv[u].y, a1); }
        }
    }
    z += z2; a0 += b0; a1 += b1;
    float r = (z > 0.f) ? 1.f / z : 0.f;   // deg==0 -> output 0
    a0 *= r; a1 *= r;
    a0 = fmaxf(a0, __shfl_xor(a0, 16)); a0 = fmaxf(a0, __shfl_xor(a0, 32));
    a1 = fmaxf(a1, __shfl_xor(a1, 16)); a1 = fmaxf(a1, __shfl_xor(a1, 32));
    if (lane < 16)
        *(float2*)(hout + ((size_t)n << 5) + (lane << 1)) = make_float2(a0, a1);
}

// ---------------- global attention pooling ----------------
__global__ __launch_bounds__(256) void k_pool(const float* __restrict__ h2, const float* __restrict__ gW,
                                              const float* __restrict__ gb, float* __restrict__ out) {
    int b = blockIdx.x, tid = threadIdx.x;
    __shared__ float ga[NPG];
    __shared__ float red[256];
    __shared__ float gws[32];
    const float* hb = h2 + (size_t)b * NPG * 32;
    if (tid < 32) gws[tid] = gW[tid];
    __syncthreads();
    float gbv = gb[0];
    float lmax = -INFINITY;
    float gloc[4];
#pragma unroll
    for (int j = 0; j < 4; ++j) {
        int nl = tid + j * 256;
        const float* row = hb + nl * 32;
        float dot = 0.f;
#pragma unroll
        for (int c = 0; c < 32; c += 4) {
            float4 v = *(const float4*)(row + c);
            dot += v.x * gws[c] + v.y * gws[c + 1] + v.z * gws[c + 2] + v.w * gws[c + 3];
        }
        gloc[j] = dot + gbv;
        lmax = fmaxf(lmax, gloc[j]);
    }
    red[tid] = lmax; __syncthreads();
    for (int s2 = 128; s2 > 0; s2 >>= 1) { if (tid < s2) red[tid] = fmaxf(red[tid], red[tid + s2]); __syncthreads(); }
    float m = red[0];
    __syncthreads();
    float lsum = 0.f;
#pragma unroll
    for (int j = 0; j < 4; ++j) {
        int nl = tid + j * 256;
        float a = __expf(gloc[j] - m);
        ga[nl] = a;
        lsum += a;
    }
    red[tid] = lsum; __syncthreads();
    for (int s2 = 128; s2 > 0; s2 >>= 1) { if (tid < s2) red[tid] += red[tid + s2]; __syncthreads(); }
    float z = red[0];
    __syncthreads();
    int d = tid & 31, ng = tid >> 5;
    float acc = 0.f;
    for (int nl = ng; nl < NPG; nl += 8) acc += ga[nl] * hb[nl * 32 + d];
    red[tid] = acc; __syncthreads();
    if (tid < 32) {
        float s = red[tid];
#pragma unroll
        for (int g2 = 1; g2 < 8; ++g2) s += red[g2 * 32 + tid];
        out[b * 32 + tid] = s / z;
    }
}

extern "C" void kernel_launch(void* const* d_in, const int* in_sizes, int n_in,
                              void* d_out, int out_size, void* d_ws, size_t ws_size,
                              hipStream_t stream) {
    const float* x     = (const float*)d_in[0];
    const int*   src   = (const int*)d_in[1];
    const int*   dst   = (const int*)d_in[2];
    const float* Ws1   = (const float*)d_in[4];
    const float* bs1   = (const float*)d_in[5];
    const float* Wd1   = (const float*)d_in[6];
    const float* bd1   = (const float*)d_in[7];
    const float* attn1 = (const float*)d_in[8];
    const float* Ws2   = (const float*)d_in[9];
    const float* bs2   = (const float*)d_in[10];
    const float* Wd2   = (const float*)d_in[11];
    const float* bd2   = (const float*)d_in[12];
    const float* attn2 = (const float*)d_in[13];
    const float* gW    = (const float*)d_in[14];
    const float* gb    = (const float*)d_in[15];
    float* out = (float*)d_out;

    // workspace layout (~89 MB)
    float* fs = (float*)d_ws;                        // N*128
    float* fd = fs + (size_t)N_NODES * 128;          // N*128
    float* h1 = fd + (size_t)N_NODES * 128;          // N*32
    float* h2 = h1 + (size_t)N_NODES * 32;           // N*32
    int* rowptr = (int*)(h2 + (size_t)N_NODES * 32); // N+1
    int* col    = rowptr + (N_NODES + 4);            // E
    // Wt planes live INSIDE the h2 region (160KB << 8.4MB); consumed by gemm1/gemm2,
    // clobbered only later by k_edge layer-2 writing h2 (strictly after gemm2).
    u16* Wt1 = (u16*)h2;                             // 4*128*128 u16 = 128KB
    u16* Wt2 = Wt1 + 4 * 128 * 128;                  // 4*128*32  u16 =  32KB

    k_wconv<<<160, 256, 0, stream>>>(Ws1, Wd1, Ws2, Wd2, Wt1, Wt2);
    k_csr<<<B_GRAPHS, 1024, 0, stream>>>(src, dst, rowptr, col);

    // layer 1
    k_gemm_mfma<128><<<N_NODES / 64, 256, 0, stream>>>(x, Wt1, bs1, bd1, fs, fd);
    k_edge<<<N_NODES / 4, 256, 0, stream>>>(fs, fd, rowptr, col, attn1, h1);

    // layer 2
    k_gemm_mfma<32><<<N_NODES / 64, 256, 0, stream>>>(h1, Wt2, bs2, bd2, fs, fd);
    k_edge<<<N_NODES / 4, 256, 0, stream>>>(fs, fd, rowptr, col, attn2, h2);

    // global attention pooling
    k_pool<<<B_GRAPHS, 256, 0, stream>>>(h2, gW, gb, out);
}